// Round 1
// baseline (358.045 us; speedup 1.0000x reference)
//
#include <hip/hip_runtime.h>

// Output: [16, 46, 526, 518] f32.  Input: [16, 32, 512, 512] f32.
// Entire 7-step pad chain composed into per-axis index maps.

#define NIN  16
#define CIN  32
#define HIN  512
#define WIN  512

#define COUT 46u
#define HOUT 526u
#define WOUT 518u

__device__ __forceinline__ int wmap(int m) {
    // reflect(+-1) -> edge(+-1) -> reflect(+-1) on W=512
    return (m < 3) ? 1 : ((m > 514) ? 510 : (m - 3));
}

__device__ __forceinline__ int hmap(int d) {
    // reflect(+-2) -> edge(+-2) -> edge(+3 front) -> reflect(+3 front) on H=512
    if (d <= 8)   return 2;
    if (d == 9)   return 1;
    if (d <= 521) return d - 10;
    return (d == 522) ? 510 : 509;
}

__device__ __forceinline__ int cmap(int g) {
    // wrap(+-1) -> wrap(+-3) -> edge(+3 back) -> reflect(+3 back) on C=32
    if (g >= 43) g = 84 - g;   // reflect back pad (size 43)
    if (g > 39)  g = 39;       // edge clamp (size 40)
    int p = g - 3;             // wrap(+-3) on size 34
    if (p < 0)   p += 34;
    if (p >= 34) p -= 34;
    // wrap(+-1) on size 32 (index into 34)
    return (p == 0) ? 31 : ((p <= 32) ? (p - 1) : 0);
}

__global__ __launch_bounds__(256) void pad_chain_kernel(const float* __restrict__ x,
                                                        float* __restrict__ out,
                                                        unsigned int nquad) {
    const unsigned int stride = gridDim.x * blockDim.x;
    for (unsigned int q = blockIdx.x * blockDim.x + threadIdx.x; q < nquad; q += stride) {
        unsigned int e  = q * 4u;
        unsigned int w  = e % WOUT;
        unsigned int t  = e / WOUT;
        unsigned int h  = t % HOUT;
        unsigned int nc = t / HOUT;
        unsigned int c  = nc % COUT;
        unsigned int n  = nc / COUT;

        float v0, v1, v2, v3;
        #pragma unroll
        for (int k = 0; k < 4; ++k) {
            const int wi = wmap((int)w);
            const int hi = hmap((int)h);
            const int ci = cmap((int)c);
            const size_t in_idx = ((((size_t)n * CIN + ci) * HIN + hi) * WIN) + wi;
            const float val = x[in_idx];
            if (k == 0) v0 = val; else if (k == 1) v1 = val; else if (k == 2) v2 = val; else v3 = val;
            // advance output coordinate by one element
            if (++w == WOUT) { w = 0; if (++h == HOUT) { h = 0; if (++c == COUT) { c = 0; ++n; } } }
        }
        float4 v = make_float4(v0, v1, v2, v3);
        reinterpret_cast<float4*>(out)[q] = v;
    }
}

extern "C" void kernel_launch(void* const* d_in, const int* in_sizes, int n_in,
                              void* d_out, int out_size, void* d_ws, size_t ws_size,
                              hipStream_t stream) {
    const float* x = (const float*)d_in[0];
    float* out = (float*)d_out;
    const unsigned int nquad = (unsigned int)(out_size / 4);   // 50,134,112
    const int threads = 256;
    const int blocks = 4096;  // grid-stride; ~48 quads/thread
    pad_chain_kernel<<<blocks, threads, 0, stream>>>(x, out, nquad);
}

// Round 2
// 296.902 us; speedup vs baseline: 1.2059x; 1.2059x over previous
//
#include <hip/hip_runtime.h>

// Output: [16, 46, 526, 518] f32.  Input: [16, 32, 512, 512] f32.
// Per output row (n,c,h):  out_row = [ in[1]x3 , in_row[0..511] , in[510]x3 ]
// where in_row = x[n, cmap(c), hmap(h), :].

__device__ __forceinline__ int hmap(int d) {
    // reflect(+-2) -> edge(+-2) -> edge(+3 front) -> reflect(+3 front) on H=512
    if (d <= 8)   return 2;
    if (d == 9)   return 1;
    if (d <= 521) return d - 10;
    return (d == 522) ? 510 : 509;
}

__device__ __forceinline__ int cmap(int g) {
    // wrap(+-1) -> wrap(+-3) -> edge(+3 back) -> reflect(+3 back) on C=32
    if (g >= 43) g = 84 - g;   // reflect back pad (size 43)
    if (g > 39)  g = 39;       // edge clamp (size 40)
    int p = g - 3;             // wrap(+-3) on size 34
    if (p < 0)   p += 34;
    if (p >= 34) p -= 34;
    // wrap(+-1) on size 32 (index into 34)
    return (p == 0) ? 31 : ((p <= 32) ? (p - 1) : 0);
}

__global__ __launch_bounds__(256) void pad_rows_kernel(const float* __restrict__ x,
                                                       float* __restrict__ out) {
    const int nc = blockIdx.y;            // n*46 + c, 0..735
    const int c  = nc % 46;               // per-block magic-div only
    const int n  = nc / 46;
    const int ci = cmap(c);

    const int half = threadIdx.x >> 7;    // 0 or 1: which of the two rows
    const int tt   = threadIdx.x & 127;   // lane within row
    const int h    = (blockIdx.x << 1) | half;   // 0..525 (526 = 2*263)
    const int hi   = hmap(h);

    const float* in_row  = x   + ((((size_t)n * 32 + ci) * 512 + hi) << 9);
    float*       out_row = out + ((size_t)nc * 526 + h) * 518;

    // interior: out[3 + 4*tt .. 3 + 4*tt + 3] = in[4*tt .. 4*tt+3]
    const float4 v = reinterpret_cast<const float4*>(in_row)[tt];   // 16B-aligned load
    *reinterpret_cast<float4*>(out_row + 3 + (tt << 2)) = v;        // 4B-aligned store

    if (tt == 0) {
        const float e = in_row[1];
        out_row[0] = e; out_row[1] = e; out_row[2] = e;
    } else if (tt == 127) {
        const float e = v.z;              // in_row[510]
        out_row[515] = e; out_row[516] = e; out_row[517] = e;
    }
}

extern "C" void kernel_launch(void* const* d_in, const int* in_sizes, int n_in,
                              void* d_out, int out_size, void* d_ws, size_t ws_size,
                              hipStream_t stream) {
    const float* x = (const float*)d_in[0];
    float* out = (float*)d_out;
    dim3 grid(263, 736);   // 263*2 = 526 rows of h, 736 = 16*46 (n,c) planes
    pad_rows_kernel<<<grid, 256, 0, stream>>>(x, out);
}